// Round 1
// 509.732 us; speedup vs baseline: 1.1255x; 1.1255x over previous
//
#include <hip/hip_runtime.h>

// ---------------- static graph constants (Traffic4cast 495x436 grid) -------
#define NN 215820          // 495*436 nodes
#define NPOOL 54064        // 248*218 pooled nodes
#define KN 53846           // kept pooled edges north/south  247*218
#define KE 53816           // kept pooled edges east/west    248*217

// output layout offsets (in floats)
static constexpr size_t OFF_POS = (size_t)NPOOL * 128;
static constexpr size_t OFF_EIN = OFF_POS + (size_t)NPOOL * 2;
static constexpr size_t OFF_EIE = OFF_EIN + (size_t)KN * 2;
static constexpr size_t OFF_EIS = OFF_EIE + (size_t)KE * 2;
static constexpr size_t OFF_EIW = OFF_EIS + (size_t)KN * 2;
static constexpr size_t OFF_EFN = OFF_EIW + (size_t)KE * 2;
static constexpr size_t OFF_EFE = OFF_EFN + (size_t)KN * 32;
static constexpr size_t OFF_EFS = OFF_EFE + (size_t)KE * 32;
static constexpr size_t OFF_EFW = OFF_EFS + (size_t)KN * 32;

typedef __attribute__((ext_vector_type(8))) short  short8v;
typedef __attribute__((ext_vector_type(4))) float  floatx4;

// W_node transposed + split into bf16 hi/lo planes: [col 0..127][k 0..255]
__device__ __align__(16) unsigned short g_wn_h[128 * 256];
__device__ __align__(16) unsigned short g_wn_l[128 * 256];

// split fp32 -> truncated bf16 hi + bf16(residual) lo; combined rel err ~2^-16
__device__ __forceinline__ void bf16split(float x, unsigned short& h,
                                          unsigned short& l) {
  const unsigned int u = __float_as_uint(x);
  h = (unsigned short)(u >> 16);
  const float hf = __uint_as_float(u & 0xffff0000u);
  l = (unsigned short)(__float_as_uint(x - hf) >> 16);
}

// ---------------------------------------------------------------------------
// Shared inner: one 32-k chunk of the 128x128 tile GEMM (used by k_xq).
// xs: [128 rows][36], ws: [32 k][132 cols]. Thread rows {4ty+i, 64+4ty+i},
// cols {4tx..4tx+3, 64+4tx..64+4tx+3}  (split keeps LDS aliasing at 2-way).
__device__ __forceinline__ void gemm_chunk(const float* __restrict__ xs,
                                           const float* __restrict__ ws,
                                           const float* const xr[8],
                                           int tx4, float acc[8][8]) {
#pragma unroll 1
  for (int kb = 0; kb < 32; kb += 4) {
    float4 xv[8];
#pragma unroll
    for (int i = 0; i < 8; ++i) xv[i] = *(const float4*)(xr[i] + kb);
    float4 wl[4], wh[4];
#pragma unroll
    for (int kk = 0; kk < 4; ++kk) {
      wl[kk] = *(const float4*)(ws + (kb + kk) * 132 + tx4);
      wh[kk] = *(const float4*)(ws + (kb + kk) * 132 + tx4 + 64);
    }
#pragma unroll
    for (int i = 0; i < 8; ++i) {
      const float* xe = (const float*)&xv[i];
#pragma unroll
      for (int kk = 0; kk < 4; ++kk) {
        acc[i][0] = fmaf(xe[kk], wl[kk].x, acc[i][0]);
        acc[i][1] = fmaf(xe[kk], wl[kk].y, acc[i][1]);
        acc[i][2] = fmaf(xe[kk], wl[kk].z, acc[i][2]);
        acc[i][3] = fmaf(xe[kk], wl[kk].w, acc[i][3]);
        acc[i][4] = fmaf(xe[kk], wh[kk].x, acc[i][4]);
        acc[i][5] = fmaf(xe[kk], wh[kk].y, acc[i][5]);
        acc[i][6] = fmaf(xe[kk], wh[kk].z, acc[i][6]);
        acc[i][7] = fmaf(xe[kk], wh[kk].w, acc[i][7]);
      }
    }
  }
}

// ---------------------------------------------------------------------------
// Kernel A: xq[q][n][u] = relu(x @ W_emb[q]) for all 4 q at once.
// Tile: 128 nodes x 128 cols (cols = 4 quadrants x 32), K=128 in 4 chunks.
__global__ __launch_bounds__(256) void k_xq(const float* __restrict__ x,
                                            const float* __restrict__ W_emb,
                                            float* __restrict__ xq) {
  __shared__ float xs[128 * 36];
  __shared__ float ws[32 * 132];
  const int t  = threadIdx.x;
  const int tx = t & 15, ty = t >> 4;
  const int n0 = blockIdx.x * 128;
  const int srow = t >> 1, soff = (t & 1) * 16;
  int snode = n0 + srow; if (snode >= NN) snode = NN - 1;
  const float* sxa = x + (size_t)snode * 128 + soff;
  float* sxd = xs + srow * 36 + soff;

  int rowidx[8];
#pragma unroll
  for (int i = 0; i < 4; ++i) { rowidx[i] = 4 * ty + i; rowidx[4 + i] = 64 + 4 * ty + i; }
  const float* xr[8];
#pragma unroll
  for (int i = 0; i < 8; ++i) xr[i] = xs + rowidx[i] * 36;
  const int tx4 = tx * 4;

  float acc[8][8];
#pragma unroll
  for (int i = 0; i < 8; ++i)
#pragma unroll
    for (int j = 0; j < 8; ++j) acc[i][j] = 0.f;

  for (int kc = 0; kc < 4; ++kc) {
    __syncthreads();
#pragma unroll
    for (int i = 0; i < 4; ++i)
      *(float4*)(sxd + 4 * i) = *(const float4*)(sxa + kc * 32 + 4 * i);
#pragma unroll
    for (int i = 0; i < 4; ++i) {
      const int f = t * 16 + 4 * i, kk = f >> 7, c = f & 127;
      *(float4*)(ws + kk * 132 + c) =
          *(const float4*)(W_emb + (size_t)(c >> 5) * 4096 +
                           (size_t)(kc * 32 + kk) * 32 + (c & 31));
    }
    __syncthreads();
    gemm_chunk(xs, ws, xr, tx4, acc);
  }
  const int qlo = tx >> 3, ulo = tx4 & 31;
#pragma unroll
  for (int i = 0; i < 8; ++i) {
    const int n = n0 + rowidx[i];
    if (n < NN) {
      float4 v, u;
      v.x = fmaxf(acc[i][0], 0.f); v.y = fmaxf(acc[i][1], 0.f);
      v.z = fmaxf(acc[i][2], 0.f); v.w = fmaxf(acc[i][3], 0.f);
      u.x = fmaxf(acc[i][4], 0.f); u.y = fmaxf(acc[i][5], 0.f);
      u.z = fmaxf(acc[i][6], 0.f); u.w = fmaxf(acc[i][7], 0.f);
      *(float4*)(xq + ((size_t)qlo * NN + n) * 32 + ulo) = v;
      *(float4*)(xq + ((size_t)(qlo + 2) * NN + n) * 32 + ulo) = u;
    }
  }
}

// ---------------------------------------------------------------------------
// Kernel C (MFMA rewrite): x2 = relu([x|agg] @ W_node) + in-register 2x2
// pooled max, via split-bf16 3-pass MFMA (hi*hi + hi*lo + lo*hi), fp32 acc.
// Block = 256 thr / 4 waves; tile = 128 nodes (2 runs of 64 cols) x 128 out.
// Wave w owns M-frags {w, w+4}  -> run-A rows 16w.. and run-B rows 64+16w..
// so every 2x2 pool group (cols i,i+1 x runs A,B) lives in ONE lane:
// cols pair = acc regs {2k,2k+1}; runs pair = acc[0]/acc[1]. Pure reg max.
// LDS tiles bf16 [row][32k], stride 64B, XOR swizzle (chunk16B ^ (row&3)):
// ds_read_b128 / ds_write_b128 both hit the 8-cycle wave floor.
__global__ __launch_bounds__(256, 4) void k_node(const float* __restrict__ x,
                                                 const float* __restrict__ agg,
                                                 float* __restrict__ out) {
  __shared__ short As_h[128 * 32], As_l[128 * 32];
  __shared__ short Bs_h[128 * 32], Bs_l[128 * 32];
  const int t   = threadIdx.x;
  const int pr  = blockIdx.y;          // pooled row 0..247
  const int pc0 = blockIdx.x * 32;     // pooled col base 0..192

  // staging: thread t handles LDS row (t>>1) chunks {t&1, (t&1)+2}
  const int srow = t >> 1, q0 = t & 1;
  int ra = (srow < 64) ? 2 * pr : 2 * pr + 1; if (ra > 494) ra = 494;
  int ca = 2 * pc0 + (srow & 63);          if (ca > 435) ca = 435;
  const size_t snode = (size_t)ra * 436 + ca;

  const int w = t >> 6, lane = t & 63;
  const int lr = lane & 15, lg = lane >> 4;

  floatx4 acc[2][8];
#pragma unroll
  for (int mi = 0; mi < 2; ++mi)
#pragma unroll
    for (int ni = 0; ni < 8; ++ni) acc[mi][ni] = (floatx4){0.f, 0.f, 0.f, 0.f};

  for (int ks = 0; ks < 8; ++ks) {
    __syncthreads();
    // ---- stage A: fp32 [x|agg] -> bf16 hi/lo, swizzled LDS
    const float* src = (ks < 4) ? (x + snode * 128 + ks * 32)
                                : (agg + snode * 128 + (ks - 4) * 32);
#pragma unroll
    for (int cc = 0; cc < 2; ++cc) {
      const int q = q0 + 2 * cc;
      const floatx4 v0 = *(const floatx4*)(src + q * 8);
      const floatx4 v1 = *(const floatx4*)(src + q * 8 + 4);
      short8v hv, lv;
#pragma unroll
      for (int j = 0; j < 4; ++j) {
        unsigned short h, l;
        bf16split(v0[j], h, l); hv[j] = (short)h; lv[j] = (short)l;
        bf16split(v1[j], h, l); hv[4 + j] = (short)h; lv[4 + j] = (short)l;
      }
      const int off = srow * 64 + ((q * 16) ^ ((srow & 3) << 4));
      *(short8v*)((char*)As_h + off) = hv;
      *(short8v*)((char*)As_l + off) = lv;
      // ---- stage B: precomputed transposed hi/lo planes of W_node
      const size_t wb = (size_t)srow * 256 + ks * 32 + q * 8;
      *(short8v*)((char*)Bs_h + off) = *(const short8v*)(g_wn_h + wb);
      *(short8v*)((char*)Bs_l + off) = *(const short8v*)(g_wn_l + wb);
    }
    __syncthreads();
    // ---- compute: frag reads + 3-pass MFMA
    short8v ah[2], al[2];
#pragma unroll
    for (int mi = 0; mi < 2; ++mi) {
      const int row = (mi ? 64 : 0) + 16 * w + lr;
      const int off = row * 64 + ((lg * 16) ^ ((row & 3) << 4));
      ah[mi] = *(const short8v*)((const char*)As_h + off);
      al[mi] = *(const short8v*)((const char*)As_l + off);
    }
#pragma unroll
    for (int ni = 0; ni < 8; ++ni) {
      const int col = 16 * ni + lr;
      const int off = col * 64 + ((lg * 16) ^ ((col & 3) << 4));
      const short8v bh = *(const short8v*)((const char*)Bs_h + off);
      const short8v bl = *(const short8v*)((const char*)Bs_l + off);
#pragma unroll
      for (int mi = 0; mi < 2; ++mi) {
        acc[mi][ni] = __builtin_amdgcn_mfma_f32_16x16x32_bf16(ah[mi], bh, acc[mi][ni], 0, 0, 0);
        acc[mi][ni] = __builtin_amdgcn_mfma_f32_16x16x32_bf16(ah[mi], bl, acc[mi][ni], 0, 0, 0);
        acc[mi][ni] = __builtin_amdgcn_mfma_f32_16x16x32_bf16(al[mi], bh, acc[mi][ni], 0, 0, 0);
      }
    }
  }
  // ---- epilogue: relu + 2x2 pooled max, all in-lane. C layout: col=lane&15,
  // row=(lane>>4)*4+reg  =>  node-col pair = regs {2k,2k+1}; runs = mi 0/1.
#pragma unroll
  for (int ni = 0; ni < 8; ++ni) {
#pragma unroll
    for (int k = 0; k < 2; ++k) {
      float v = fmaxf(fmaxf(acc[0][ni][2 * k], acc[0][ni][2 * k + 1]),
                      fmaxf(acc[1][ni][2 * k], acc[1][ni][2 * k + 1]));
      v = fmaxf(v, 0.f);
      const int pc = pc0 + 8 * w + 2 * lg + k;
      if (pc < 218) out[((size_t)pr * 218 + pc) * 128 + 16 * ni + lr] = v;
    }
  }
}

// ---------------------------------------------------------------------------
// Kernel B: edge MLP, one 32-lane slot per PAIR of edges in the same pooled
// dup-group (closed-form indices). efeat = in-thread max -> plain store.
// wcol[96] persistent in VGPRs, amortized over ~26 pairs via grid-stride.
__global__ __launch_bounds__(256) void k_edge(
    const float* __restrict__ ef_n, const float* __restrict__ ef_e,
    const float* __restrict__ ef_s, const float* __restrict__ ef_w,
    const float* __restrict__ xq, const float* __restrict__ W_edge,
    float* __restrict__ agg, float* __restrict__ out) {
  const int q = blockIdx.y;
  const float* ef; float* efb; int P;
  if (q == 0)      { ef = ef_n; P = 107692; efb = out + OFF_EFN; }
  else if (q == 1) { ef = ef_e; P = 107880; efb = out + OFF_EFE; }
  else if (q == 2) { ef = ef_s; P = 107692; efb = out + OFF_EFS; }
  else             { ef = ef_w; P = 107880; efb = out + OFF_EFW; }
  const int j = threadIdx.x & 31, slot = threadIdx.x >> 5;
  const float* Wq = W_edge + q * 3072;
  float wcol[96];
#pragma unroll
  for (int k = 0; k < 96; ++k) wcol[k] = Wq[k * 32 + j];
  const float* xqq = xq + (size_t)q * NN * 32;
  __shared__ float ein[8][192];
  float* row = ein[slot];

  for (int p = blockIdx.x * 8 + slot; p < P; p += gridDim.x * 8) {
    int e1, src1, dst1, e2, src2, dst2, kidx; bool kept, has2;
    if (q == 0) {                       // north: pair cols 2pc,2pc+1, row r
      const int rp = p / 218, pc = p - rp * 218;
      const int r = rp + 1, c = 2 * pc;
      e1 = (r - 1) * 436 + c; e2 = e1 + 1;
      src1 = r * 436 + c; dst1 = src1 - 436;
      src2 = src1 + 1; dst2 = dst1 + 1; has2 = true;
      kept = (r & 1) == 0; kidx = ((r >> 1) - 1) * 218 + pc;
    } else if (q == 2) {                // south
      const int r = p / 218, pc = p - r * 218;
      const int c = 2 * pc;
      e1 = r * 436 + c; e2 = e1 + 1;
      src1 = e1; dst1 = src1 + 436;
      src2 = src1 + 1; dst2 = dst1 + 1; has2 = true;
      kept = (r & 1) == 1; kidx = (r >> 1) * 218 + pc;
    } else if (q == 1) {                // east: pair rows 2pr,2pr+1, col c
      const int pr = p / 435, c = p - pr * 435;
      e1 = 2 * pr * 435 + c; e2 = e1 + 435;
      src1 = 2 * pr * 436 + c; dst1 = src1 + 1;
      src2 = src1 + 436; dst2 = dst1 + 436;
      has2 = pr < 247;
      kept = (c & 1) == 1; kidx = pr * 217 + (c >> 1);
    } else {                            // west
      const int pr = p / 435, cm = p - pr * 435;
      const int c = cm + 1;
      e1 = 2 * pr * 435 + cm; e2 = e1 + 435;
      src1 = 2 * pr * 436 + c; dst1 = src1 - 1;
      src2 = src1 + 436; dst2 = dst1 + 436;
      has2 = pr < 247;
      kept = (c & 1) == 0; kidx = pr * 217 + (c >> 1) - 1;
    }
    const int e2c = has2 ? e2 : e1;
    const int s2c = has2 ? src2 : src1;
    const int d2c = has2 ? dst2 : dst1;
    row[j]       = ef[(size_t)e1 * 32 + j];
    row[32 + j]  = xqq[(size_t)src1 * 32 + j];
    row[64 + j]  = xqq[(size_t)dst1 * 32 + j];
    row[96 + j]  = ef[(size_t)e2c * 32 + j];
    row[128 + j] = xqq[(size_t)s2c * 32 + j];
    row[160 + j] = xqq[(size_t)d2c * 32 + j];
    // wave-private LDS row: compiler inserts lgkmcnt before dependent reads
    float a1 = 0.f, a2 = 0.f;
#pragma unroll
    for (int kq = 0; kq < 24; ++kq) {
      const float4 b1 = *(const float4*)&row[4 * kq];
      const float4 b2 = *(const float4*)&row[96 + 4 * kq];
      a1 = fmaf(b1.x, wcol[4 * kq + 0], a1); a1 = fmaf(b1.y, wcol[4 * kq + 1], a1);
      a1 = fmaf(b1.z, wcol[4 * kq + 2], a1); a1 = fmaf(b1.w, wcol[4 * kq + 3], a1);
      a2 = fmaf(b2.x, wcol[4 * kq + 0], a2); a2 = fmaf(b2.y, wcol[4 * kq + 1], a2);
      a2 = fmaf(b2.z, wcol[4 * kq + 2], a2); a2 = fmaf(b2.w, wcol[4 * kq + 3], a2);
    }
    const float f1 = fmaxf(a1, 0.f), f2 = fmaxf(a2, 0.f);
    agg[(size_t)dst1 * 128 + q * 32 + j] = f1 * 0.25f;
    if (has2) agg[(size_t)dst2 * 128 + q * 32 + j] = f2 * 0.25f;
    if (kept) efb[(size_t)kidx * 32 + j] = has2 ? fmaxf(f1, f2) : f1;
  }
}

// ---------------------------------------------------------------------------
// Kernel D: zero agg boundary strips (nodes with no in-edge per direction)
// + closed-form new_pos + pooled edge indices + W_node transpose/split prep.
__global__ __launch_bounds__(256) void k_misc(float* __restrict__ out,
                                              float* __restrict__ agg,
                                              const float* __restrict__ W_node) {
  int u = blockIdx.x * 256 + threadIdx.x;
  if (u < 436 * 32) {  // north: dst row 494 missing
    agg[((size_t)494 * 436 + (u >> 5)) * 128 + (u & 31)] = 0.f; return;
  }
  u -= 436 * 32;
  if (u < 495 * 32) {  // east: dst col 0 missing
    agg[(size_t)(u >> 5) * 436 * 128 + 32 + (u & 31)] = 0.f; return;
  }
  u -= 495 * 32;
  if (u < 436 * 32) {  // south: dst row 0 missing
    agg[(size_t)(u >> 5) * 128 + 64 + (u & 31)] = 0.f; return;
  }
  u -= 436 * 32;
  if (u < 495 * 32) {  // west: dst col 435 missing
    agg[((size_t)(u >> 5) * 436 + 435) * 128 + 96 + (u & 31)] = 0.f; return;
  }
  u -= 495 * 32;
  if (u < NPOOL * 2) {
    const int p  = u >> 1;
    const int pr = p / 218, pc = p - pr * 218;
    out[OFF_POS + u] = (float)((u & 1) ? pc : pr); return;
  }
  u -= NPOOL * 2;
  if (u < KN * 2) {   // north
    const int e  = u >> 1;
    const int kr = e / 218 + 1, pc = e - (kr - 1) * 218;
    const int s  = kr * 218 + pc;
    out[OFF_EIN + u] = (float)((u & 1) ? (s - 218) : s); return;
  }
  u -= KN * 2;
  if (u < KE * 2) {   // east
    const int e  = u >> 1;
    const int pr = e / 217, jj = e - pr * 217;
    const int s  = pr * 218 + jj;
    out[OFF_EIE + u] = (float)((u & 1) ? (s + 1) : s); return;
  }
  u -= KE * 2;
  if (u < KN * 2) {   // south
    const int e  = u >> 1;
    const int k  = e / 218, pc = e - k * 218;
    const int s  = k * 218 + pc;
    out[OFF_EIS + u] = (float)((u & 1) ? (s + 218) : s); return;
  }
  u -= KN * 2;
  if (u < KE * 2) {   // west
    const int e  = u >> 1;
    const int pr = e / 217, jj = e - pr * 217;
    const int s  = pr * 218 + jj + 1;
    out[OFF_EIW + u] = (float)((u & 1) ? (s - 1) : s); return;
  }
  u -= KE * 2;
  if (u < 256 * 128) { // W_node [k][c] -> transposed bf16 hi/lo planes [c][k]
    const int k = u >> 7, c = u & 127;
    unsigned short h, l;
    bf16split(W_node[u], h, l);
    g_wn_h[(size_t)c * 256 + k] = h;
    g_wn_l[(size_t)c * 256 + k] = l;
  }
}

// ---------------------------------------------------------------------------
extern "C" void kernel_launch(void* const* d_in, const int* in_sizes, int n_in,
                              void* d_out, int out_size, void* d_ws, size_t ws_size,
                              hipStream_t stream) {
  const float* x      = (const float*)d_in[0];
  const float* ef_n   = (const float*)d_in[6];
  const float* ef_e   = (const float*)d_in[7];
  const float* ef_s   = (const float*)d_in[8];
  const float* ef_w   = (const float*)d_in[9];
  const float* W_emb  = (const float*)d_in[10];
  const float* W_edge = (const float*)d_in[11];
  const float* W_node = (const float*)d_in[12];
  float* out = (float*)d_out;

  float* xq  = (float*)d_ws;                 // [4][NN][32]
  float* agg = xq + (size_t)NN * 128;        // [NN][128]

  const int misc_total = (436 + 495 + 436 + 495) * 32 + NPOOL * 2 +
                         2 * (KN * 2 + KE * 2) + 256 * 128;
  k_misc<<<dim3((misc_total + 255) / 256), 256, 0, stream>>>(out, agg, W_node);
  k_xq  <<<dim3((NN + 127) / 128), 256, 0, stream>>>(x, W_emb, xq);
  k_edge<<<dim3(512, 4), 256, 0, stream>>>(ef_n, ef_e, ef_s, ef_w,
                                           xq, W_edge, agg, out);
  k_node<<<dim3(7, 248), 256, 0, stream>>>(x, agg, out);
}

// Round 2
// 466.968 us; speedup vs baseline: 1.2285x; 1.0916x over previous
//
#include <hip/hip_runtime.h>

// ---------------- static graph constants (Traffic4cast 495x436 grid) -------
#define NN 215820          // 495*436 nodes
#define NPOOL 54064        // 248*218 pooled nodes
#define KN 53846           // kept pooled edges north/south  247*218
#define KE 53816           // kept pooled edges east/west    248*217

// output layout offsets (in floats)
static constexpr size_t OFF_POS = (size_t)NPOOL * 128;
static constexpr size_t OFF_EIN = OFF_POS + (size_t)NPOOL * 2;
static constexpr size_t OFF_EIE = OFF_EIN + (size_t)KN * 2;
static constexpr size_t OFF_EIS = OFF_EIE + (size_t)KE * 2;
static constexpr size_t OFF_EIW = OFF_EIS + (size_t)KN * 2;
static constexpr size_t OFF_EFN = OFF_EIW + (size_t)KE * 2;
static constexpr size_t OFF_EFE = OFF_EFN + (size_t)KN * 32;
static constexpr size_t OFF_EFS = OFF_EFE + (size_t)KE * 32;
static constexpr size_t OFF_EFW = OFF_EFS + (size_t)KN * 32;

typedef __attribute__((ext_vector_type(8))) short  short8v;
typedef __attribute__((ext_vector_type(4))) float  floatx4;

// W_node transposed + split into bf16 hi/lo planes: [col 0..127][k 0..255]
__device__ __align__(16) unsigned short g_wn_h[128 * 256];
__device__ __align__(16) unsigned short g_wn_l[128 * 256];
// W_emb transposed + split: [col = q*32+u (0..127)][k 0..127]
__device__ __align__(16) unsigned short g_we_h[128 * 128];
__device__ __align__(16) unsigned short g_we_l[128 * 128];

// split fp32 -> truncated bf16 hi + bf16(residual) lo; combined rel err ~2^-16
__device__ __forceinline__ void bf16split(float x, unsigned short& h,
                                          unsigned short& l) {
  const unsigned int u = __float_as_uint(x);
  h = (unsigned short)(u >> 16);
  const float hf = __uint_as_float(u & 0xffff0000u);
  l = (unsigned short)(__float_as_uint(x - hf) >> 16);
}

// ---------------------------------------------------------------------------
// Kernel A (MFMA): xq[q][n][u] = relu(x @ W_emb[q]) for all 4 q at once.
// Same engine as k_node: 128-node x 128-col tile, K=128 in 4 chunks,
// split-bf16 3-pass MFMA. B = g_we planes prepped by k_misc.
__global__ __launch_bounds__(256, 4) void k_xq(const float* __restrict__ x,
                                               float* __restrict__ xq) {
  __shared__ __align__(16) short As_h[128 * 32], As_l[128 * 32];
  __shared__ __align__(16) short Bs_h[128 * 32], Bs_l[128 * 32];
  const int t  = threadIdx.x;
  const int n0 = blockIdx.x * 128;
  const int srow = t >> 1, q0 = t & 1;
  int sn = n0 + srow; if (sn >= NN) sn = NN - 1;
  const float* srcx = x + (size_t)sn * 128;
  const int w = t >> 6, lane = t & 63;
  const int lr = lane & 15, lg = lane >> 4;

  floatx4 acc[2][8];
#pragma unroll
  for (int mi = 0; mi < 2; ++mi)
#pragma unroll
    for (int ni = 0; ni < 8; ++ni) acc[mi][ni] = (floatx4){0.f, 0.f, 0.f, 0.f};

  for (int ks = 0; ks < 4; ++ks) {
    __syncthreads();
#pragma unroll
    for (int cc = 0; cc < 2; ++cc) {
      const int q = q0 + 2 * cc;
      const floatx4 v0 = *(const floatx4*)(srcx + ks * 32 + q * 8);
      const floatx4 v1 = *(const floatx4*)(srcx + ks * 32 + q * 8 + 4);
      short8v hv, lv;
#pragma unroll
      for (int j = 0; j < 4; ++j) {
        unsigned short h, l;
        bf16split(v0[j], h, l); hv[j] = (short)h; lv[j] = (short)l;
        bf16split(v1[j], h, l); hv[4 + j] = (short)h; lv[4 + j] = (short)l;
      }
      const int off = srow * 64 + ((q * 16) ^ ((srow & 3) << 4));
      *(short8v*)((char*)As_h + off) = hv;
      *(short8v*)((char*)As_l + off) = lv;
      const size_t wb = (size_t)srow * 128 + ks * 32 + q * 8;
      *(short8v*)((char*)Bs_h + off) = *(const short8v*)(g_we_h + wb);
      *(short8v*)((char*)Bs_l + off) = *(const short8v*)(g_we_l + wb);
    }
    __syncthreads();
    short8v ah[2], al[2];
#pragma unroll
    for (int mi = 0; mi < 2; ++mi) {
      const int row = (mi ? 64 : 0) + 16 * w + lr;
      const int off = row * 64 + ((lg * 16) ^ ((row & 3) << 4));
      ah[mi] = *(const short8v*)((const char*)As_h + off);
      al[mi] = *(const short8v*)((const char*)As_l + off);
    }
#pragma unroll
    for (int ni = 0; ni < 8; ++ni) {
      const int col = 16 * ni + lr;
      const int off = col * 64 + ((lg * 16) ^ ((col & 3) << 4));
      const short8v bh = *(const short8v*)((const char*)Bs_h + off);
      const short8v bl = *(const short8v*)((const char*)Bs_l + off);
#pragma unroll
      for (int mi = 0; mi < 2; ++mi) {
        acc[mi][ni] = __builtin_amdgcn_mfma_f32_16x16x32_bf16(ah[mi], bh, acc[mi][ni], 0, 0, 0);
        acc[mi][ni] = __builtin_amdgcn_mfma_f32_16x16x32_bf16(ah[mi], bl, acc[mi][ni], 0, 0, 0);
        acc[mi][ni] = __builtin_amdgcn_mfma_f32_16x16x32_bf16(al[mi], bh, acc[mi][ni], 0, 0, 0);
      }
    }
  }
  // epilogue: relu + store. C layout: col=lane&15, row=4*lg+reg (verified in
  // k_node round 1). col = q*32+u; n = n0 + 64*mi + 16*w + 4*lg + r.
#pragma unroll
  for (int ni = 0; ni < 8; ++ni) {
    const int col = 16 * ni + lr;
    const int qq = col >> 5, u = col & 31;
#pragma unroll
    for (int mi = 0; mi < 2; ++mi) {
      const int nb = n0 + (mi ? 64 : 0) + 16 * w + 4 * lg;
#pragma unroll
      for (int r = 0; r < 4; ++r) {
        const int n = nb + r;
        if (n < NN)
          xq[((size_t)qq * NN + n) * 32 + u] = fmaxf(acc[mi][ni][r], 0.f);
      }
    }
  }
}

// ---------------------------------------------------------------------------
// Kernel C (MFMA): x2 = relu([x|agg] @ W_node) + in-register 2x2 pooled max,
// split-bf16 3-pass MFMA, fp32 acc. (verified round 1 — unchanged)
__global__ __launch_bounds__(256, 4) void k_node(const float* __restrict__ x,
                                                 const float* __restrict__ agg,
                                                 float* __restrict__ out) {
  __shared__ short As_h[128 * 32], As_l[128 * 32];
  __shared__ short Bs_h[128 * 32], Bs_l[128 * 32];
  const int t   = threadIdx.x;
  const int pr  = blockIdx.y;          // pooled row 0..247
  const int pc0 = blockIdx.x * 32;     // pooled col base 0..192

  const int srow = t >> 1, q0 = t & 1;
  int ra = (srow < 64) ? 2 * pr : 2 * pr + 1; if (ra > 494) ra = 494;
  int ca = 2 * pc0 + (srow & 63);          if (ca > 435) ca = 435;
  const size_t snode = (size_t)ra * 436 + ca;

  const int w = t >> 6, lane = t & 63;
  const int lr = lane & 15, lg = lane >> 4;

  floatx4 acc[2][8];
#pragma unroll
  for (int mi = 0; mi < 2; ++mi)
#pragma unroll
    for (int ni = 0; ni < 8; ++ni) acc[mi][ni] = (floatx4){0.f, 0.f, 0.f, 0.f};

  for (int ks = 0; ks < 8; ++ks) {
    __syncthreads();
    const float* src = (ks < 4) ? (x + snode * 128 + ks * 32)
                                : (agg + snode * 128 + (ks - 4) * 32);
#pragma unroll
    for (int cc = 0; cc < 2; ++cc) {
      const int q = q0 + 2 * cc;
      const floatx4 v0 = *(const floatx4*)(src + q * 8);
      const floatx4 v1 = *(const floatx4*)(src + q * 8 + 4);
      short8v hv, lv;
#pragma unroll
      for (int j = 0; j < 4; ++j) {
        unsigned short h, l;
        bf16split(v0[j], h, l); hv[j] = (short)h; lv[j] = (short)l;
        bf16split(v1[j], h, l); hv[4 + j] = (short)h; lv[4 + j] = (short)l;
      }
      const int off = srow * 64 + ((q * 16) ^ ((srow & 3) << 4));
      *(short8v*)((char*)As_h + off) = hv;
      *(short8v*)((char*)As_l + off) = lv;
      const size_t wb = (size_t)srow * 256 + ks * 32 + q * 8;
      *(short8v*)((char*)Bs_h + off) = *(const short8v*)(g_wn_h + wb);
      *(short8v*)((char*)Bs_l + off) = *(const short8v*)(g_wn_l + wb);
    }
    __syncthreads();
    short8v ah[2], al[2];
#pragma unroll
    for (int mi = 0; mi < 2; ++mi) {
      const int row = (mi ? 64 : 0) + 16 * w + lr;
      const int off = row * 64 + ((lg * 16) ^ ((row & 3) << 4));
      ah[mi] = *(const short8v*)((const char*)As_h + off);
      al[mi] = *(const short8v*)((const char*)As_l + off);
    }
#pragma unroll
    for (int ni = 0; ni < 8; ++ni) {
      const int col = 16 * ni + lr;
      const int off = col * 64 + ((lg * 16) ^ ((col & 3) << 4));
      const short8v bh = *(const short8v*)((const char*)Bs_h + off);
      const short8v bl = *(const short8v*)((const char*)Bs_l + off);
#pragma unroll
      for (int mi = 0; mi < 2; ++mi) {
        acc[mi][ni] = __builtin_amdgcn_mfma_f32_16x16x32_bf16(ah[mi], bh, acc[mi][ni], 0, 0, 0);
        acc[mi][ni] = __builtin_amdgcn_mfma_f32_16x16x32_bf16(ah[mi], bl, acc[mi][ni], 0, 0, 0);
        acc[mi][ni] = __builtin_amdgcn_mfma_f32_16x16x32_bf16(al[mi], bh, acc[mi][ni], 0, 0, 0);
      }
    }
  }
#pragma unroll
  for (int ni = 0; ni < 8; ++ni) {
#pragma unroll
    for (int k = 0; k < 2; ++k) {
      float v = fmaxf(fmaxf(acc[0][ni][2 * k], acc[0][ni][2 * k + 1]),
                      fmaxf(acc[1][ni][2 * k], acc[1][ni][2 * k + 1]));
      v = fmaxf(v, 0.f);
      const int pc = pc0 + 8 * w + 2 * lg + k;
      if (pc < 218) out[((size_t)pr * 218 + pc) * 128 + 16 * ni + lr] = v;
    }
  }
}

// ---------------------------------------------------------------------------
// Kernel B: edge MLP, one 32-lane slot per PAIR of edges in the same pooled
// dup-group (closed-form indices). efeat = in-thread max -> plain store.
__global__ __launch_bounds__(256) void k_edge(
    const float* __restrict__ ef_n, const float* __restrict__ ef_e,
    const float* __restrict__ ef_s, const float* __restrict__ ef_w,
    const float* __restrict__ xq, const float* __restrict__ W_edge,
    float* __restrict__ agg, float* __restrict__ out) {
  const int q = blockIdx.y;
  const float* ef; float* efb; int P;
  if (q == 0)      { ef = ef_n; P = 107692; efb = out + OFF_EFN; }
  else if (q == 1) { ef = ef_e; P = 107880; efb = out + OFF_EFE; }
  else if (q == 2) { ef = ef_s; P = 107692; efb = out + OFF_EFS; }
  else             { ef = ef_w; P = 107880; efb = out + OFF_EFW; }
  const int j = threadIdx.x & 31, slot = threadIdx.x >> 5;
  const float* Wq = W_edge + q * 3072;
  float wcol[96];
#pragma unroll
  for (int k = 0; k < 96; ++k) wcol[k] = Wq[k * 32 + j];
  const float* xqq = xq + (size_t)q * NN * 32;
  __shared__ float ein[8][192];
  float* row = ein[slot];

  for (int p = blockIdx.x * 8 + slot; p < P; p += gridDim.x * 8) {
    int e1, src1, dst1, e2, src2, dst2, kidx; bool kept, has2;
    if (q == 0) {                       // north: pair cols 2pc,2pc+1, row r
      const int rp = p / 218, pc = p - rp * 218;
      const int r = rp + 1, c = 2 * pc;
      e1 = (r - 1) * 436 + c; e2 = e1 + 1;
      src1 = r * 436 + c; dst1 = src1 - 436;
      src2 = src1 + 1; dst2 = dst1 + 1; has2 = true;
      kept = (r & 1) == 0; kidx = ((r >> 1) - 1) * 218 + pc;
    } else if (q == 2) {                // south
      const int r = p / 218, pc = p - r * 218;
      const int c = 2 * pc;
      e1 = r * 436 + c; e2 = e1 + 1;
      src1 = e1; dst1 = src1 + 436;
      src2 = src1 + 1; dst2 = dst1 + 1; has2 = true;
      kept = (r & 1) == 1; kidx = (r >> 1) * 218 + pc;
    } else if (q == 1) {                // east: pair rows 2pr,2pr+1, col c
      const int pr = p / 435, c = p - pr * 435;
      e1 = 2 * pr * 435 + c; e2 = e1 + 435;
      src1 = 2 * pr * 436 + c; dst1 = src1 + 1;
      src2 = src1 + 436; dst2 = dst1 + 436;
      has2 = pr < 247;
      kept = (c & 1) == 1; kidx = pr * 217 + (c >> 1);
    } else {                            // west
      const int pr = p / 435, cm = p - pr * 435;
      const int c = cm + 1;
      e1 = 2 * pr * 435 + cm; e2 = e1 + 435;
      src1 = 2 * pr * 436 + c; dst1 = src1 - 1;
      src2 = src1 + 436; dst2 = dst1 + 436;
      has2 = pr < 247;
      kept = (c & 1) == 0; kidx = pr * 217 + (c >> 1) - 1;
    }
    const int e2c = has2 ? e2 : e1;
    const int s2c = has2 ? src2 : src1;
    const int d2c = has2 ? dst2 : dst1;
    row[j]       = ef[(size_t)e1 * 32 + j];
    row[32 + j]  = xqq[(size_t)src1 * 32 + j];
    row[64 + j]  = xqq[(size_t)dst1 * 32 + j];
    row[96 + j]  = ef[(size_t)e2c * 32 + j];
    row[128 + j] = xqq[(size_t)s2c * 32 + j];
    row[160 + j] = xqq[(size_t)d2c * 32 + j];
    // wave-private LDS row: compiler inserts lgkmcnt before dependent reads
    float a1 = 0.f, a2 = 0.f;
#pragma unroll
    for (int kq = 0; kq < 24; ++kq) {
      const float4 b1 = *(const float4*)&row[4 * kq];
      const float4 b2 = *(const float4*)&row[96 + 4 * kq];
      a1 = fmaf(b1.x, wcol[4 * kq + 0], a1); a1 = fmaf(b1.y, wcol[4 * kq + 1], a1);
      a1 = fmaf(b1.z, wcol[4 * kq + 2], a1); a1 = fmaf(b1.w, wcol[4 * kq + 3], a1);
      a2 = fmaf(b2.x, wcol[4 * kq + 0], a2); a2 = fmaf(b2.y, wcol[4 * kq + 1], a2);
      a2 = fmaf(b2.z, wcol[4 * kq + 2], a2); a2 = fmaf(b2.w, wcol[4 * kq + 3], a2);
    }
    const float f1 = fmaxf(a1, 0.f), f2 = fmaxf(a2, 0.f);
    agg[(size_t)dst1 * 128 + q * 32 + j] = f1 * 0.25f;
    if (has2) agg[(size_t)dst2 * 128 + q * 32 + j] = f2 * 0.25f;
    if (kept) efb[(size_t)kidx * 32 + j] = has2 ? fmaxf(f1, f2) : f1;
  }
}

// ---------------------------------------------------------------------------
// Kernel D: zero agg boundary strips + closed-form new_pos + pooled edge
// indices + W_node / W_emb transpose-split prep.
__global__ __launch_bounds__(256) void k_misc(float* __restrict__ out,
                                              float* __restrict__ agg,
                                              const float* __restrict__ W_node,
                                              const float* __restrict__ W_emb) {
  int u = blockIdx.x * 256 + threadIdx.x;
  if (u < 436 * 32) {  // north: dst row 494 missing
    agg[((size_t)494 * 436 + (u >> 5)) * 128 + (u & 31)] = 0.f; return;
  }
  u -= 436 * 32;
  if (u < 495 * 32) {  // east: dst col 0 missing
    agg[(size_t)(u >> 5) * 436 * 128 + 32 + (u & 31)] = 0.f; return;
  }
  u -= 495 * 32;
  if (u < 436 * 32) {  // south: dst row 0 missing
    agg[(size_t)(u >> 5) * 128 + 64 + (u & 31)] = 0.f; return;
  }
  u -= 436 * 32;
  if (u < 495 * 32) {  // west: dst col 435 missing
    agg[((size_t)(u >> 5) * 436 + 435) * 128 + 96 + (u & 31)] = 0.f; return;
  }
  u -= 495 * 32;
  if (u < NPOOL * 2) {
    const int p  = u >> 1;
    const int pr = p / 218, pc = p - pr * 218;
    out[OFF_POS + u] = (float)((u & 1) ? pc : pr); return;
  }
  u -= NPOOL * 2;
  if (u < KN * 2) {   // north
    const int e  = u >> 1;
    const int kr = e / 218 + 1, pc = e - (kr - 1) * 218;
    const int s  = kr * 218 + pc;
    out[OFF_EIN + u] = (float)((u & 1) ? (s - 218) : s); return;
  }
  u -= KN * 2;
  if (u < KE * 2) {   // east
    const int e  = u >> 1;
    const int pr = e / 217, jj = e - pr * 217;
    const int s  = pr * 218 + jj;
    out[OFF_EIE + u] = (float)((u & 1) ? (s + 1) : s); return;
  }
  u -= KE * 2;
  if (u < KN * 2) {   // south
    const int e  = u >> 1;
    const int k  = e / 218, pc = e - k * 218;
    const int s  = k * 218 + pc;
    out[OFF_EIS + u] = (float)((u & 1) ? (s + 218) : s); return;
  }
  u -= KN * 2;
  if (u < KE * 2) {   // west
    const int e  = u >> 1;
    const int pr = e / 217, jj = e - pr * 217;
    const int s  = pr * 218 + jj + 1;
    out[OFF_EIW + u] = (float)((u & 1) ? (s - 1) : s); return;
  }
  u -= KE * 2;
  if (u < 256 * 128) { // W_node [k][c] -> transposed bf16 hi/lo planes [c][k]
    const int k = u >> 7, c = u & 127;
    unsigned short h, l;
    bf16split(W_node[u], h, l);
    g_wn_h[(size_t)c * 256 + k] = h;
    g_wn_l[(size_t)c * 256 + k] = l;
    return;
  }
  u -= 256 * 128;
  if (u < 4 * 128 * 32) { // W_emb [q][k][uu] -> planes [(q*32+uu)][k]
    const int q = u >> 12, k = (u >> 5) & 127, uu = u & 31;
    unsigned short h, l;
    bf16split(W_emb[u], h, l);
    g_we_h[(size_t)(q * 32 + uu) * 128 + k] = h;
    g_we_l[(size_t)(q * 32 + uu) * 128 + k] = l;
  }
}

// ---------------------------------------------------------------------------
extern "C" void kernel_launch(void* const* d_in, const int* in_sizes, int n_in,
                              void* d_out, int out_size, void* d_ws, size_t ws_size,
                              hipStream_t stream) {
  const float* x      = (const float*)d_in[0];
  const float* ef_n   = (const float*)d_in[6];
  const float* ef_e   = (const float*)d_in[7];
  const float* ef_s   = (const float*)d_in[8];
  const float* ef_w   = (const float*)d_in[9];
  const float* W_emb  = (const float*)d_in[10];
  const float* W_edge = (const float*)d_in[11];
  const float* W_node = (const float*)d_in[12];
  float* out = (float*)d_out;

  float* xq  = (float*)d_ws;                 // [4][NN][32]
  float* agg = xq + (size_t)NN * 128;        // [NN][128]

  const int misc_total = (436 + 495 + 436 + 495) * 32 + NPOOL * 2 +
                         2 * (KN * 2 + KE * 2) + 256 * 128 + 4 * 128 * 32;
  k_misc<<<dim3((misc_total + 255) / 256), 256, 0, stream>>>(out, agg,
                                                             W_node, W_emb);
  k_xq  <<<dim3((NN + 127) / 128), 256, 0, stream>>>(x, xq);
  k_edge<<<dim3(512, 4), 256, 0, stream>>>(ef_n, ef_e, ef_s, ef_w,
                                           xq, W_edge, agg, out);
  k_node<<<dim3(7, 248), 256, 0, stream>>>(x, agg, out);
}

// Round 3
// 448.849 us; speedup vs baseline: 1.2781x; 1.0404x over previous
//
#include <hip/hip_runtime.h>

// ---------------- static graph constants (Traffic4cast 495x436 grid) -------
#define NN 215820          // 495*436 nodes
#define NPOOL 54064        // 248*218 pooled nodes
#define KN 53846           // kept pooled edges north/south  247*218
#define KE 53816           // kept pooled edges east/west    248*217

// output layout offsets (in floats)
static constexpr size_t OFF_POS = (size_t)NPOOL * 128;
static constexpr size_t OFF_EIN = OFF_POS + (size_t)NPOOL * 2;
static constexpr size_t OFF_EIE = OFF_EIN + (size_t)KN * 2;
static constexpr size_t OFF_EIS = OFF_EIE + (size_t)KE * 2;
static constexpr size_t OFF_EIW = OFF_EIS + (size_t)KN * 2;
static constexpr size_t OFF_EFN = OFF_EIW + (size_t)KE * 2;
static constexpr size_t OFF_EFE = OFF_EFN + (size_t)KN * 32;
static constexpr size_t OFF_EFS = OFF_EFE + (size_t)KE * 32;
static constexpr size_t OFF_EFW = OFF_EFS + (size_t)KN * 32;

typedef __attribute__((ext_vector_type(8))) short  short8v;
typedef __attribute__((ext_vector_type(4))) float  floatx4;

// W_node transposed + split into bf16 hi/lo planes: [col 0..127][k 0..255]
__device__ __align__(16) unsigned short g_wn_h[128 * 256];
__device__ __align__(16) unsigned short g_wn_l[128 * 256];
// W_emb transposed + split: [col = q*32+u (0..127)][k 0..127]
__device__ __align__(16) unsigned short g_we_h[128 * 128];
__device__ __align__(16) unsigned short g_we_l[128 * 128];
// W_edge transposed + split: [q*32+col (0..127)][k 0..95]
__device__ __align__(16) unsigned short g_wd_h[128 * 96];
__device__ __align__(16) unsigned short g_wd_l[128 * 96];

// split fp32 -> truncated bf16 hi + bf16(residual) lo; combined rel err ~2^-16
__device__ __forceinline__ void bf16split(float x, unsigned short& h,
                                          unsigned short& l) {
  const unsigned int u = __float_as_uint(x);
  h = (unsigned short)(u >> 16);
  const float hf = __uint_as_float(u & 0xffff0000u);
  l = (unsigned short)(__float_as_uint(x - hf) >> 16);
}

// ---------------------------------------------------------------------------
// Kernel A (MFMA): xq[q][n][u] = relu(x @ W_emb[q]) for all 4 q at once.
__global__ __launch_bounds__(256, 4) void k_xq(const float* __restrict__ x,
                                               float* __restrict__ xq) {
  __shared__ __align__(16) short As_h[128 * 32], As_l[128 * 32];
  __shared__ __align__(16) short Bs_h[128 * 32], Bs_l[128 * 32];
  const int t  = threadIdx.x;
  const int n0 = blockIdx.x * 128;
  const int srow = t >> 1, q0 = t & 1;
  int sn = n0 + srow; if (sn >= NN) sn = NN - 1;
  const float* srcx = x + (size_t)sn * 128;
  const int w = t >> 6, lane = t & 63;
  const int lr = lane & 15, lg = lane >> 4;

  floatx4 acc[2][8];
#pragma unroll
  for (int mi = 0; mi < 2; ++mi)
#pragma unroll
    for (int ni = 0; ni < 8; ++ni) acc[mi][ni] = (floatx4){0.f, 0.f, 0.f, 0.f};

  for (int ks = 0; ks < 4; ++ks) {
    __syncthreads();
#pragma unroll
    for (int cc = 0; cc < 2; ++cc) {
      const int q = q0 + 2 * cc;
      const floatx4 v0 = *(const floatx4*)(srcx + ks * 32 + q * 8);
      const floatx4 v1 = *(const floatx4*)(srcx + ks * 32 + q * 8 + 4);
      short8v hv, lv;
#pragma unroll
      for (int j = 0; j < 4; ++j) {
        unsigned short h, l;
        bf16split(v0[j], h, l); hv[j] = (short)h; lv[j] = (short)l;
        bf16split(v1[j], h, l); hv[4 + j] = (short)h; lv[4 + j] = (short)l;
      }
      const int off = srow * 64 + ((q * 16) ^ ((srow & 3) << 4));
      *(short8v*)((char*)As_h + off) = hv;
      *(short8v*)((char*)As_l + off) = lv;
      const size_t wb = (size_t)srow * 128 + ks * 32 + q * 8;
      *(short8v*)((char*)Bs_h + off) = *(const short8v*)(g_we_h + wb);
      *(short8v*)((char*)Bs_l + off) = *(const short8v*)(g_we_l + wb);
    }
    __syncthreads();
    short8v ah[2], al[2];
#pragma unroll
    for (int mi = 0; mi < 2; ++mi) {
      const int row = (mi ? 64 : 0) + 16 * w + lr;
      const int off = row * 64 + ((lg * 16) ^ ((row & 3) << 4));
      ah[mi] = *(const short8v*)((const char*)As_h + off);
      al[mi] = *(const short8v*)((const char*)As_l + off);
    }
#pragma unroll
    for (int ni = 0; ni < 8; ++ni) {
      const int col = 16 * ni + lr;
      const int off = col * 64 + ((lg * 16) ^ ((col & 3) << 4));
      const short8v bh = *(const short8v*)((const char*)Bs_h + off);
      const short8v bl = *(const short8v*)((const char*)Bs_l + off);
#pragma unroll
      for (int mi = 0; mi < 2; ++mi) {
        acc[mi][ni] = __builtin_amdgcn_mfma_f32_16x16x32_bf16(ah[mi], bh, acc[mi][ni], 0, 0, 0);
        acc[mi][ni] = __builtin_amdgcn_mfma_f32_16x16x32_bf16(ah[mi], bl, acc[mi][ni], 0, 0, 0);
        acc[mi][ni] = __builtin_amdgcn_mfma_f32_16x16x32_bf16(al[mi], bh, acc[mi][ni], 0, 0, 0);
      }
    }
  }
#pragma unroll
  for (int ni = 0; ni < 8; ++ni) {
    const int col = 16 * ni + lr;
    const int qq = col >> 5, u = col & 31;
#pragma unroll
    for (int mi = 0; mi < 2; ++mi) {
      const int nb = n0 + (mi ? 64 : 0) + 16 * w + 4 * lg;
#pragma unroll
      for (int r = 0; r < 4; ++r) {
        const int n = nb + r;
        if (n < NN)
          xq[((size_t)qq * NN + n) * 32 + u] = fmaxf(acc[mi][ni][r], 0.f);
      }
    }
  }
}

// ---------------------------------------------------------------------------
// Kernel C (MFMA): x2 = relu([x|agg] @ W_node) + in-register 2x2 pooled max.
__global__ __launch_bounds__(256, 4) void k_node(const float* __restrict__ x,
                                                 const float* __restrict__ agg,
                                                 float* __restrict__ out) {
  __shared__ short As_h[128 * 32], As_l[128 * 32];
  __shared__ short Bs_h[128 * 32], Bs_l[128 * 32];
  const int t   = threadIdx.x;
  const int pr  = blockIdx.y;          // pooled row 0..247
  const int pc0 = blockIdx.x * 32;     // pooled col base 0..192

  const int srow = t >> 1, q0 = t & 1;
  int ra = (srow < 64) ? 2 * pr : 2 * pr + 1; if (ra > 494) ra = 494;
  int ca = 2 * pc0 + (srow & 63);          if (ca > 435) ca = 435;
  const size_t snode = (size_t)ra * 436 + ca;

  const int w = t >> 6, lane = t & 63;
  const int lr = lane & 15, lg = lane >> 4;

  floatx4 acc[2][8];
#pragma unroll
  for (int mi = 0; mi < 2; ++mi)
#pragma unroll
    for (int ni = 0; ni < 8; ++ni) acc[mi][ni] = (floatx4){0.f, 0.f, 0.f, 0.f};

  for (int ks = 0; ks < 8; ++ks) {
    __syncthreads();
    const float* src = (ks < 4) ? (x + snode * 128 + ks * 32)
                                : (agg + snode * 128 + (ks - 4) * 32);
#pragma unroll
    for (int cc = 0; cc < 2; ++cc) {
      const int q = q0 + 2 * cc;
      const floatx4 v0 = *(const floatx4*)(src + q * 8);
      const floatx4 v1 = *(const floatx4*)(src + q * 8 + 4);
      short8v hv, lv;
#pragma unroll
      for (int j = 0; j < 4; ++j) {
        unsigned short h, l;
        bf16split(v0[j], h, l); hv[j] = (short)h; lv[j] = (short)l;
        bf16split(v1[j], h, l); hv[4 + j] = (short)h; lv[4 + j] = (short)l;
      }
      const int off = srow * 64 + ((q * 16) ^ ((srow & 3) << 4));
      *(short8v*)((char*)As_h + off) = hv;
      *(short8v*)((char*)As_l + off) = lv;
      const size_t wb = (size_t)srow * 256 + ks * 32 + q * 8;
      *(short8v*)((char*)Bs_h + off) = *(const short8v*)(g_wn_h + wb);
      *(short8v*)((char*)Bs_l + off) = *(const short8v*)(g_wn_l + wb);
    }
    __syncthreads();
    short8v ah[2], al[2];
#pragma unroll
    for (int mi = 0; mi < 2; ++mi) {
      const int row = (mi ? 64 : 0) + 16 * w + lr;
      const int off = row * 64 + ((lg * 16) ^ ((row & 3) << 4));
      ah[mi] = *(const short8v*)((const char*)As_h + off);
      al[mi] = *(const short8v*)((const char*)As_l + off);
    }
#pragma unroll
    for (int ni = 0; ni < 8; ++ni) {
      const int col = 16 * ni + lr;
      const int off = col * 64 + ((lg * 16) ^ ((col & 3) << 4));
      const short8v bh = *(const short8v*)((const char*)Bs_h + off);
      const short8v bl = *(const short8v*)((const char*)Bs_l + off);
#pragma unroll
      for (int mi = 0; mi < 2; ++mi) {
        acc[mi][ni] = __builtin_amdgcn_mfma_f32_16x16x32_bf16(ah[mi], bh, acc[mi][ni], 0, 0, 0);
        acc[mi][ni] = __builtin_amdgcn_mfma_f32_16x16x32_bf16(ah[mi], bl, acc[mi][ni], 0, 0, 0);
        acc[mi][ni] = __builtin_amdgcn_mfma_f32_16x16x32_bf16(al[mi], bh, acc[mi][ni], 0, 0, 0);
      }
    }
  }
#pragma unroll
  for (int ni = 0; ni < 8; ++ni) {
#pragma unroll
    for (int k = 0; k < 2; ++k) {
      float v = fmaxf(fmaxf(acc[0][ni][2 * k], acc[0][ni][2 * k + 1]),
                      fmaxf(acc[1][ni][2 * k], acc[1][ni][2 * k + 1]));
      v = fmaxf(v, 0.f);
      const int pc = pc0 + 8 * w + 2 * lg + k;
      if (pc < 218) out[((size_t)pr * 218 + pc) * 128 + 16 * ni + lr] = v;
    }
  }
}

// ---------------------------------------------------------------------------
// Kernel B (MFMA rewrite): edge MLP as [128 edges][96] @ [96][32] GEMM.
// K-chunks ARE the concat: kc0=ef, kc1=xq[src], kc2=xq[dst] — all contiguous
// 128x32 fp32 slabs (grid edges are consecutive). Tiles:
//  N/S: 1 grid row x 128 cols  -> pooled pair = adjacent cols = regs 2k/2k+1
//  E/W: 2 grid rows x 64 cols  -> pooled pair = run A/B = acc[0]/acc[1]
// Tail tiles clamp-and-overlap (idempotent). E/W pr=247 clamps run B = run A
// (duplicate stores of identical values; pair max degenerates correctly).
__global__ __launch_bounds__(256, 4) void k_edge(
    const float* __restrict__ ef_n, const float* __restrict__ ef_e,
    const float* __restrict__ ef_s, const float* __restrict__ ef_w,
    const float* __restrict__ xq, float* __restrict__ agg,
    float* __restrict__ out) {
  __shared__ __align__(16) short As_h[128 * 32], As_l[128 * 32];
  __shared__ __align__(16) short Bs_h[32 * 32],  Bs_l[32 * 32];
  const int t = threadIdx.x;
  int b = blockIdx.x;

  // ---- decode tile: N 494x4 | S 494x4 | E 248x7 | W 248x7
  int q, row = 0, pr = 0, c0;
  const float* ef; float* efb;
  if (b < 1976)        { q = 0; ef = ef_n; efb = out + OFF_EFN;
                         row = b >> 2; c0 = (b & 3) * 128; if (c0 > 308) c0 = 308; }
  else if (b < 3952)   { b -= 1976; q = 2; ef = ef_s; efb = out + OFF_EFS;
                         row = b >> 2; c0 = (b & 3) * 128; if (c0 > 308) c0 = 308; }
  else if (b < 5688)   { b -= 3952; q = 1; ef = ef_e; efb = out + OFF_EFE;
                         pr = b / 7;  c0 = (b - pr * 7) * 64; if (c0 > 371) c0 = 371; }
  else                 { b -= 5688; q = 3; ef = ef_w; efb = out + OFF_EFW;
                         pr = b / 7;  c0 = (b - pr * 7) * 64; if (c0 > 371) c0 = 371; }
  const float* xqq = xq + (size_t)q * NN * 32;

  // ---- per-thread staging bases for the 3 K-chunks
  const int srow = t >> 1, q0 = t & 1;
  const float *base0, *base1, *base2;
  if (q == 0) {                       // north: erow=row; src=e+436, dst=e
    const int e = row * 436 + c0 + srow;
    base0 = ef  + (size_t)e * 32;
    base1 = xqq + (size_t)(e + 436) * 32;
    base2 = xqq + (size_t)e * 32;
  } else if (q == 2) {                // south: src=e, dst=e+436
    const int e = row * 436 + c0 + srow;
    base0 = ef  + (size_t)e * 32;
    base1 = xqq + (size_t)e * 32;
    base2 = xqq + (size_t)(e + 436) * 32;
  } else {
    int r = 2 * pr + (srow >> 6); if (r > 494) r = 494;
    const int cc = c0 + (srow & 63);
    if (q == 1) {                     // east: src=r*436+c, dst=src+1
      base0 = ef  + ((size_t)r * 435 + cc) * 32;
      base1 = xqq + ((size_t)r * 436 + cc) * 32;
      base2 = base1 + 32;
    } else {                          // west: cm=cc, c=cc+1, dst=src-1
      base0 = ef  + ((size_t)r * 435 + cc) * 32;
      base1 = xqq + ((size_t)r * 436 + cc + 1) * 32;
      base2 = base1 - 32;
    }
  }

  const int w = t >> 6, lane = t & 63;
  const int lr = lane & 15, lg = lane >> 4;

  floatx4 acc[2][2];
#pragma unroll
  for (int mi = 0; mi < 2; ++mi)
#pragma unroll
    for (int ni = 0; ni < 2; ++ni) acc[mi][ni] = (floatx4){0.f, 0.f, 0.f, 0.f};

  for (int kc = 0; kc < 3; ++kc) {
    __syncthreads();
    const float* src = (kc == 0) ? base0 : (kc == 1) ? base1 : base2;
#pragma unroll
    for (int cc = 0; cc < 2; ++cc) {
      const int qch = q0 + 2 * cc;
      const floatx4 v0 = *(const floatx4*)(src + qch * 8);
      const floatx4 v1 = *(const floatx4*)(src + qch * 8 + 4);
      short8v hv, lv;
#pragma unroll
      for (int j = 0; j < 4; ++j) {
        unsigned short h, l;
        bf16split(v0[j], h, l); hv[j] = (short)h; lv[j] = (short)l;
        bf16split(v1[j], h, l); hv[4 + j] = (short)h; lv[4 + j] = (short)l;
      }
      const int off = srow * 64 + ((qch * 16) ^ ((srow & 3) << 4));
      *(short8v*)((char*)As_h + off) = hv;
      *(short8v*)((char*)As_l + off) = lv;
    }
    if (t < 128) {                    // B: 32 cols x 32 k from g_wd planes
      const int col = t >> 2, ch = t & 3;
      const size_t wb = (size_t)(q * 32 + col) * 96 + kc * 32 + ch * 8;
      const int off = col * 64 + ((ch * 16) ^ ((col & 3) << 4));
      *(short8v*)((char*)Bs_h + off) = *(const short8v*)(g_wd_h + wb);
      *(short8v*)((char*)Bs_l + off) = *(const short8v*)(g_wd_l + wb);
    }
    __syncthreads();
    short8v ah[2], al[2], bh[2], bl[2];
#pragma unroll
    for (int mi = 0; mi < 2; ++mi) {
      const int rowm = 64 * mi + 16 * w + lr;
      const int off = rowm * 64 + ((lg * 16) ^ ((rowm & 3) << 4));
      ah[mi] = *(const short8v*)((const char*)As_h + off);
      al[mi] = *(const short8v*)((const char*)As_l + off);
    }
#pragma unroll
    for (int ni = 0; ni < 2; ++ni) {
      const int col = 16 * ni + lr;
      const int off = col * 64 + ((lg * 16) ^ ((col & 3) << 4));
      bh[ni] = *(const short8v*)((const char*)Bs_h + off);
      bl[ni] = *(const short8v*)((const char*)Bs_l + off);
    }
#pragma unroll
    for (int ni = 0; ni < 2; ++ni)
#pragma unroll
      for (int mi = 0; mi < 2; ++mi) {
        acc[mi][ni] = __builtin_amdgcn_mfma_f32_16x16x32_bf16(ah[mi], bh[ni], acc[mi][ni], 0, 0, 0);
        acc[mi][ni] = __builtin_amdgcn_mfma_f32_16x16x32_bf16(ah[mi], bl[ni], acc[mi][ni], 0, 0, 0);
        acc[mi][ni] = __builtin_amdgcn_mfma_f32_16x16x32_bf16(al[mi], bh[ni], acc[mi][ni], 0, 0, 0);
      }
  }

  // ---- epilogue: relu; agg scatter; pooled-max efeat
  float vv[2][2][4];
#pragma unroll
  for (int mi = 0; mi < 2; ++mi)
#pragma unroll
    for (int ni = 0; ni < 2; ++ni)
#pragma unroll
      for (int r = 0; r < 4; ++r) vv[mi][ni][r] = fmaxf(acc[mi][ni][r], 0.f);

#pragma unroll
  for (int ni = 0; ni < 2; ++ni) {
    const int colo = q * 32 + 16 * ni + lr;
#pragma unroll
    for (int mi = 0; mi < 2; ++mi) {
      size_t dstb;
      if (q == 0)      dstb = (size_t)row * 436 + c0 + 64 * mi + 16 * w + 4 * lg;
      else if (q == 2) dstb = (size_t)(row + 1) * 436 + c0 + 64 * mi + 16 * w + 4 * lg;
      else {
        int r2 = 2 * pr + mi; if (r2 > 494) r2 = 494;
        dstb = (size_t)r2 * 436 + c0 + 16 * w + 4 * lg + (q == 1 ? 1 : 0);
      }
#pragma unroll
      for (int r = 0; r < 4; ++r)
        agg[(dstb + r) * 128 + colo] = vv[mi][ni][r] * 0.25f;
    }
  }

  if (q == 0 || q == 2) {
    if (row & 1) {                    // kept rows: north erow odd, south r odd
      const int krow = row >> 1;
#pragma unroll
      for (int ni = 0; ni < 2; ++ni)
#pragma unroll
        for (int mi = 0; mi < 2; ++mi)
#pragma unroll
          for (int k = 0; k < 2; ++k) {
            const int c = c0 + 64 * mi + 16 * w + 4 * lg + 2 * k;
            const int kidx = krow * 218 + (c >> 1);
            const float val = fmaxf(vv[mi][ni][2 * k], vv[mi][ni][2 * k + 1]);
            efb[(size_t)kidx * 32 + 16 * ni + lr] = val;
          }
    }
  } else {
#pragma unroll
    for (int ni = 0; ni < 2; ++ni)
#pragma unroll
      for (int r = 0; r < 4; ++r) {
        const int jj = 16 * w + 4 * lg + r;
        const int c = c0 + jj + (q == 3 ? 1 : 0);
        const bool kept = (q == 1) ? ((c & 1) == 1) : ((c & 1) == 0);
        if (kept) {
          const int kidx = pr * 217 + (c >> 1) - (q == 3 ? 1 : 0);
          const float val = fmaxf(vv[0][ni][r], vv[1][ni][r]);
          efb[(size_t)kidx * 32 + 16 * ni + lr] = val;
        }
      }
  }
}

// ---------------------------------------------------------------------------
// Kernel D: zero agg boundary strips + closed-form new_pos + pooled edge
// indices + W_node / W_emb / W_edge transpose-split prep.
__global__ __launch_bounds__(256) void k_misc(float* __restrict__ out,
                                              float* __restrict__ agg,
                                              const float* __restrict__ W_node,
                                              const float* __restrict__ W_emb,
                                              const float* __restrict__ W_edge) {
  int u = blockIdx.x * 256 + threadIdx.x;
  if (u < 436 * 32) {  // north: dst row 494 missing
    agg[((size_t)494 * 436 + (u >> 5)) * 128 + (u & 31)] = 0.f; return;
  }
  u -= 436 * 32;
  if (u < 495 * 32) {  // east: dst col 0 missing
    agg[(size_t)(u >> 5) * 436 * 128 + 32 + (u & 31)] = 0.f; return;
  }
  u -= 495 * 32;
  if (u < 436 * 32) {  // south: dst row 0 missing
    agg[(size_t)(u >> 5) * 128 + 64 + (u & 31)] = 0.f; return;
  }
  u -= 436 * 32;
  if (u < 495 * 32) {  // west: dst col 435 missing
    agg[((size_t)(u >> 5) * 436 + 435) * 128 + 96 + (u & 31)] = 0.f; return;
  }
  u -= 495 * 32;
  if (u < NPOOL * 2) {
    const int p  = u >> 1;
    const int pr = p / 218, pc = p - pr * 218;
    out[OFF_POS + u] = (float)((u & 1) ? pc : pr); return;
  }
  u -= NPOOL * 2;
  if (u < KN * 2) {   // north
    const int e  = u >> 1;
    const int kr = e / 218 + 1, pc = e - (kr - 1) * 218;
    const int s  = kr * 218 + pc;
    out[OFF_EIN + u] = (float)((u & 1) ? (s - 218) : s); return;
  }
  u -= KN * 2;
  if (u < KE * 2) {   // east
    const int e  = u >> 1;
    const int pr = e / 217, jj = e - pr * 217;
    const int s  = pr * 218 + jj;
    out[OFF_EIE + u] = (float)((u & 1) ? (s + 1) : s); return;
  }
  u -= KE * 2;
  if (u < KN * 2) {   // south
    const int e  = u >> 1;
    const int k  = e / 218, pc = e - k * 218;
    const int s  = k * 218 + pc;
    out[OFF_EIS + u] = (float)((u & 1) ? (s + 218) : s); return;
  }
  u -= KN * 2;
  if (u < KE * 2) {   // west
    const int e  = u >> 1;
    const int pr = e / 217, jj = e - pr * 217;
    const int s  = pr * 218 + jj + 1;
    out[OFF_EIW + u] = (float)((u & 1) ? (s - 1) : s); return;
  }
  u -= KE * 2;
  if (u < 256 * 128) { // W_node [k][c] -> transposed bf16 hi/lo planes [c][k]
    const int k = u >> 7, c = u & 127;
    unsigned short h, l;
    bf16split(W_node[u], h, l);
    g_wn_h[(size_t)c * 256 + k] = h;
    g_wn_l[(size_t)c * 256 + k] = l;
    return;
  }
  u -= 256 * 128;
  if (u < 4 * 128 * 32) { // W_emb [q][k][uu] -> planes [(q*32+uu)][k]
    const int q = u >> 12, k = (u >> 5) & 127, uu = u & 31;
    unsigned short h, l;
    bf16split(W_emb[u], h, l);
    g_we_h[(size_t)(q * 32 + uu) * 128 + k] = h;
    g_we_l[(size_t)(q * 32 + uu) * 128 + k] = l;
    return;
  }
  u -= 4 * 128 * 32;
  if (u < 4 * 96 * 32) { // W_edge [q][k][col] -> planes [(q*32+col)][k 0..95]
    const int q = u / 3072, rem = u - q * 3072;
    const int k = rem >> 5, col = rem & 31;
    unsigned short h, l;
    bf16split(W_edge[u], h, l);
    g_wd_h[(size_t)(q * 32 + col) * 96 + k] = h;
    g_wd_l[(size_t)(q * 32 + col) * 96 + k] = l;
  }
}

// ---------------------------------------------------------------------------
extern "C" void kernel_launch(void* const* d_in, const int* in_sizes, int n_in,
                              void* d_out, int out_size, void* d_ws, size_t ws_size,
                              hipStream_t stream) {
  const float* x      = (const float*)d_in[0];
  const float* ef_n   = (const float*)d_in[6];
  const float* ef_e   = (const float*)d_in[7];
  const float* ef_s   = (const float*)d_in[8];
  const float* ef_w   = (const float*)d_in[9];
  const float* W_emb  = (const float*)d_in[10];
  const float* W_edge = (const float*)d_in[11];
  const float* W_node = (const float*)d_in[12];
  float* out = (float*)d_out;

  float* xq  = (float*)d_ws;                 // [4][NN][32]
  float* agg = xq + (size_t)NN * 128;        // [NN][128]

  const int misc_total = (436 + 495 + 436 + 495) * 32 + NPOOL * 2 +
                         2 * (KN * 2 + KE * 2) + 256 * 128 + 4 * 128 * 32 +
                         4 * 96 * 32;
  k_misc<<<dim3((misc_total + 255) / 256), 256, 0, stream>>>(out, agg, W_node,
                                                             W_emb, W_edge);
  k_xq  <<<dim3((NN + 127) / 128), 256, 0, stream>>>(x, xq);
  k_edge<<<dim3(7424), 256, 0, stream>>>(ef_n, ef_e, ef_s, ef_w,
                                         xq, agg, out);
  k_node<<<dim3(7, 248), 256, 0, stream>>>(x, agg, out);
}